// Round 6
// baseline (170.684 us; speedup 1.0000x reference)
//
#include <hip/hip_runtime.h>
#include <math.h>

#define EPS 1e-5f

typedef _Float16 f16x8 __attribute__((ext_vector_type(8)));
typedef _Float16 f16x4 __attribute__((ext_vector_type(4)));
typedef float    f32x4 __attribute__((ext_vector_type(4)));

// ---------------- K0: weight packing + BN coefficient prep ----------------
__global__ void k0_prep(const float* __restrict__ c2w, const float* __restrict__ c3w,
                        const float* __restrict__ c2b, const float* __restrict__ bn2g,
                        const float* __restrict__ bn2b, const float* __restrict__ bn2m,
                        const float* __restrict__ bn2v,
                        const float* __restrict__ c3b, const float* __restrict__ bn3g,
                        const float* __restrict__ bn3b, const float* __restrict__ bn3m,
                        const float* __restrict__ bn3v,
                        const float* __restrict__ mw_in, const float* __restrict__ mw_out,
                        const float* __restrict__ f1w, const float* __restrict__ f1b,
                        const float* __restrict__ bn4g, const float* __restrict__ bn4b,
                        const float* __restrict__ bn4m, const float* __restrict__ bn4v,
                        const float* __restrict__ c1w, const float* __restrict__ c1b,
                        const float* __restrict__ bn1g, const float* __restrict__ bn1b,
                        const float* __restrict__ bn1m, const float* __restrict__ bn1v,
                        _Float16* __restrict__ wA2h, _Float16* __restrict__ wA3h,
                        _Float16* __restrict__ wInH, _Float16* __restrict__ wOutH,
                        _Float16* __restrict__ f1H, _Float16* __restrict__ wA1h,
                        float* __restrict__ scbi) {
  int idx = blockIdx.x * blockDim.x + threadIdx.x;
  int stride = gridDim.x * blockDim.x;
  for (int i = idx; i < 172032; i += stride) {
    int j = i & 7; int t = i >> 3; int co = t & 127; int sg = t >> 7;
    int kglob = sg * 8 + j;
    int ci = kglob & 63, kk = kglob >> 6;
    wA2h[i] = (_Float16)c2w[(co * 64 + ci) * 21 + kk];
  }
  for (int i = idx; i < 294912; i += stride) {
    int j = i & 7; int t = i >> 3; int co = t & 255; int sg = t >> 8;
    int kglob = sg * 8 + j;
    int ci = kglob & 127, kk = kglob >> 7;
    wA3h[i] = (_Float16)c3w[(co * 128 + ci) * 9 + kk];
  }
  for (int i = idx; i < 1216 * 256; i += stride) {
    int row = i >> 8;
    wInH[i] = (row < 1160) ? (_Float16)mw_in[i] : (_Float16)0.f;
  }
  for (int i = idx; i < 256 * 512; i += stride) wOutH[i] = (_Float16)mw_out[i];
  for (int i = idx; i < 64 * 256; i += stride)  f1H[i]  = (_Float16)f1w[i];
  for (int i = idx; i < 4096; i += stride) {
    int kglob = i & 63, co = i >> 6;
    int r = kglob >> 4, q = kglob & 15;
    int k = 4 * q + r;
    wA1h[i] = (k < 51) ? (_Float16)c1w[co * 51 + k] : (_Float16)0.f;
  }
  if (idx < 128) {
    float sc = bn2g[idx] / sqrtf(bn2v[idx] + EPS);
    scbi[idx] = sc;
    scbi[128 + idx] = (c2b[idx] - bn2m[idx]) * sc + bn2b[idx];
  }
  if (idx < 256) {
    float sc = bn3g[idx] / sqrtf(bn3v[idx] + EPS);
    scbi[256 + idx] = sc;
    scbi[512 + idx] = (c3b[idx] - bn3m[idx]) * sc + bn3b[idx];
  }
  if (idx < 64) {
    float sc = bn4g[idx] / sqrtf(bn4v[idx] + EPS);
    scbi[768 + idx] = sc;
    scbi[832 + idx] = (f1b[idx] - bn4m[idx]) * sc + bn4b[idx];
  }
  if (idx >= 64 && idx < 128) {
    int c = idx - 64;
    float sc = bn1g[c] / sqrtf(bn1v[c] + EPS);
    scbi[896 + c] = sc;
    scbi[960 + c] = (c1b[c] - bn1m[c]) * sc + bn1b[c];
  }
}

// ---------------- K123: fused conv1+pool -> conv2 -> conv3 -> w-mean ----------------
// R6: 16-wave (1024-thread) restructure for occupancy. Grid is pinned at
// 512 blocks (one per batch-row) = 2 blocks/CU; at 8 waves/block that was
// 4 waves/SIMD (32% occupancy) and ~30% idle no per-wave pipelining could
// remove (R4/R5 null). 16 waves/block -> 8 waves/SIMD (full occupancy).
// Tiles: conv2 wave = (co group of 32: wv>>2) x (w quarter of 32: wv&3),
// mm=2/nn=2 -- block-total LDS B-traffic unchanged (16x4 = 8x8 reads),
// A-traffic x2 but L1-resident (8KB/step slice). conv3 wave = (co chunk
// of 32: wv>>1) x (w half of 32: wv&1) with scratch pair-reduce for the
// w-mean. A-prefetch: simple use-then-reload (8 waves/SIMD TLP covers L2
// latency; saves 16 VGPR to fit the <=64 VGPR needed for 8 waves/SIMD).
// s_setprio(1) wraps MFMA clusters (independent-wave regime).
__global__ __launch_bounds__(1024, 8) void k123_conv123(
    const float* __restrict__ x, const _Float16* __restrict__ wA1h,
    const _Float16* __restrict__ wA2h, const _Float16* __restrict__ wA3h,
    const float* __restrict__ scbi, float* __restrict__ part) {
  __shared__ float phx[4 * 980];                 // conv1 phase arrays x_r[t]
  __shared__ __align__(16) _Float16 buf[18432];  // xT [288][64] -> h2T [144][128] -> f32 scratch
  _Float16* xT  = buf;
  _Float16* h2T = buf;
  int br = blockIdx.x, tid = threadIdx.x;
  // ---- stage: zero phx and xT pad rows ----
  for (int i = tid; i < 3920; i += 1024) phx[i] = 0.f;
  {
    float4 z4 = make_float4(0.f, 0.f, 0.f, 0.f);
    for (int i = tid; i < 80; i += 1024)  ((float4*)xT)[i] = z4;            // rows 0..9
    for (int i = tid; i < 304; i += 1024) ((float4*)(xT + 16000))[i] = z4;  // rows 250..287
  }
  __syncthreads();
  const float* xrow = x + (size_t)br * 3840;
  for (int i = tid; i < 960; i += 1024) {
    float4 v = ((const float4*)xrow)[i];
    int g = 4 * i;
    #pragma unroll
    for (int c = 0; c < 4; ++c) {
      int gp = g + c + 25;                 // = 4t + r
      phx[(gp & 3) * 980 + (gp >> 2)] = ((const float*)&v)[c];
    }
  }
  int l = tid & 63, wv = tid >> 6;      // wv 0..15
  int lr = l & 15, lg = l >> 4;
  // ---- conv1 phase: 16 waves, per-wave groups g = wv + 16*it (g<60) ----
  {
    f16x8 af1[2][4];
    #pragma unroll
    for (int s = 0; s < 2; ++s)
      #pragma unroll
      for (int mm = 0; mm < 4; ++mm)
        af1[s][mm] = *(const f16x8*)&wA1h[(mm * 16 + lr) * 64 + s * 32 + lg * 8];
    float scr[4][4], bir[4][4];
    #pragma unroll
    for (int mm = 0; mm < 4; ++mm)
      #pragma unroll
      for (int r2 = 0; r2 < 4; ++r2) {
        int co = mm * 16 + lg * 4 + r2;
        scr[mm][r2] = scbi[896 + co];
        bir[mm][r2] = scbi[960 + co];
      }
    __syncthreads();   // phx + pad zeros visible
    for (int it = 0; it < 4; ++it) {
      int g = wv + 16 * it;
      if (g < 60) {
        int w0 = g * 16;
        f32x4 acc1[4] = {};
        #pragma unroll
        for (int s = 0; s < 2; ++s) {
          int r = s * 2 + (lg >> 1), q0 = (lg & 1) * 8;
          const float* src = &phx[r * 980 + w0 + lr + q0];
          f16x8 bf;
          #pragma unroll
          for (int j = 0; j < 8; ++j) bf[j] = (_Float16)src[j];
          #pragma unroll
          for (int mm = 0; mm < 4; ++mm)
            acc1[mm] = __builtin_amdgcn_mfma_f32_16x16x32_f16(af1[s][mm], bf, acc1[mm], 0, 0, 0);
        }
        int pp = w0 / 4 + (lr >> 2);       // pooled index 0..239
        int p = pp + 10;                   // xT row
        int cpx = (p >> 1) & 7;
        #pragma unroll
        for (int mm = 0; mm < 4; ++mm) {
          int co0 = mm * 16 + lg * 4;
          f16x4 hv;
          #pragma unroll
          for (int r2 = 0; r2 < 4; ++r2) {
            float v0 = acc1[mm][r2] * scr[mm][r2] + bir[mm][r2];
            float m1 = fmaxf(v0, __shfl_xor(v0, 1));
            float m2 = fmaxf(m1, __shfl_xor(m1, 2));
            hv[r2] = (_Float16)fmaxf(m2, 0.f);
          }
          if ((lr & 3) == 0)
            *(f16x4*)&xT[p * 64 + ((co0 >> 3) ^ cpx) * 8 + (co0 & 7)] = hv;
        }
      }
    }
  }
  // ---- conv2 phase: wave = (co group of 32: wv>>2) x (w quarter of 32: wv&3) ----
  int cobase = (wv >> 2) * 32, wbase = (wv & 3) * 32;
  int arow2 = lg * 128 + cobase + lr;
  int wn[2], wn128[2];
  #pragma unroll
  for (int nn = 0; nn < 2; ++nn) { wn[nn] = wbase + nn * 16 + lr; wn128[nn] = wn[nn] * 128; }
  f32x4 acc[2][2] = {};
  const _Float16* wa2 = wA2h + (size_t)arow2 * 8;   // step s at wa2[s*4096 + mm*128]
  f16x8 afE[2], afO[2];
  afE[0] = *(const f16x8*)&wa2[0];
  afE[1] = *(const f16x8*)&wa2[128];
  afO[0] = *(const f16x8*)&wa2[4096];
  afO[1] = *(const f16x8*)&wa2[4096 + 128];
  __syncthreads();   // xT fully written
  #pragma unroll 1
  for (int sp = 0; sp < 21; ++sp) {         // pair of K-steps s=2sp, 2sp+1 (kk=sp for both)
    int sp64 = sp * 64;
    int sph = sp >> 1;
    f16x8 bf0[2], bf1[2];
    #pragma unroll
    for (int nn = 0; nn < 2; ++nn) {
      int t = (wn[nn] + sph) & 7;
      int i0 = wn128[nn] + sp64 + ((lg ^ t) << 3);  // half-index; even step (cc=lg)
      bf0[nn] = *(const f16x8*)&xT[i0];
      bf1[nn] = *(const f16x8*)&xT[i0 ^ 32];        // odd step: cc=4+lg -> ^32 halves
    }
    __builtin_amdgcn_s_setprio(1);
    #pragma unroll
    for (int mm = 0; mm < 2; ++mm)
      #pragma unroll
      for (int nn = 0; nn < 2; ++nn)
        acc[mm][nn] = __builtin_amdgcn_mfma_f32_16x16x32_f16(afE[mm], bf0[nn], acc[mm][nn], 0, 0, 0);
    __builtin_amdgcn_s_setprio(0);
    if (sp < 20) {
      const _Float16* wsrc = wa2 + (size_t)(2 * sp + 2) * 4096;
      afE[0] = *(const f16x8*)&wsrc[0];
      afE[1] = *(const f16x8*)&wsrc[128];
    }
    __builtin_amdgcn_s_setprio(1);
    #pragma unroll
    for (int mm = 0; mm < 2; ++mm)
      #pragma unroll
      for (int nn = 0; nn < 2; ++nn)
        acc[mm][nn] = __builtin_amdgcn_mfma_f32_16x16x32_f16(afO[mm], bf1[nn], acc[mm][nn], 0, 0, 0);
    __builtin_amdgcn_s_setprio(0);
    if (sp < 20) {
      const _Float16* wsrc = wa2 + (size_t)(2 * sp + 3) * 4096;
      afO[0] = *(const f16x8*)&wsrc[0];
      afO[1] = *(const f16x8*)&wsrc[128];
    }
  }
  __syncthreads();   // all xT reads done; buf may now be overwritten as h2T
  // conv2 epilogue: BN+ReLU -> h2T (aliased buf), plus pad-row zeroing
  {
    float4 z4 = make_float4(0.f, 0.f, 0.f, 0.f);
    for (int i = tid; i < 384; i += 1024) {
      int h8 = (i < 64) ? i : (1984 + (i - 64));
      *(float4*)&h2T[h8 * 8] = z4;
    }
    const float* sc2 = scbi;
    const float* bi2 = scbi + 128;
    #pragma unroll
    for (int mm = 0; mm < 2; ++mm) {
      int co0 = cobase + mm * 16 + lg * 4;
      float s0 = sc2[co0], s1 = sc2[co0 + 1], s2 = sc2[co0 + 2], s3 = sc2[co0 + 3];
      float b0 = bi2[co0], b1 = bi2[co0 + 1], b2 = bi2[co0 + 2], b3 = bi2[co0 + 3];
      #pragma unroll
      for (int nn = 0; nn < 2; ++nn) {
        int w = wn[nn];
        if (w < 120) {
          int p3 = 4 + w;
          f16x4 hv;
          hv[0] = (_Float16)fmaxf(acc[mm][nn][0] * s0 + b0, 0.f);
          hv[1] = (_Float16)fmaxf(acc[mm][nn][1] * s1 + b1, 0.f);
          hv[2] = (_Float16)fmaxf(acc[mm][nn][2] * s2 + b2, 0.f);
          hv[3] = (_Float16)fmaxf(acc[mm][nn][3] * s3 + b3, 0.f);
          int cp = (co0 >> 3) ^ ((p3 >> 1) & 15);
          *(f16x4*)&h2T[p3 * 128 + cp * 8 + (co0 & 7)] = hv;
        }
      }
    }
  }
  // ---- conv3 phase: wave = (co chunk of 32: wv>>1) x (w half of 32: wv&1) ----
  int cobase3 = (wv >> 1) * 32, wbase3 = (wv & 1) * 32;
  int arow3 = lg * 256 + cobase3 + lr;
  const _Float16* wa3 = wA3h + (size_t)arow3 * 8;   // step s at wa3[s*8192 + mm*128]
  int wn3[2], wn256[2];
  #pragma unroll
  for (int nn = 0; nn < 2; ++nn) { wn3[nn] = wbase3 + nn * 16 + lr; wn256[nn] = wn3[nn] * 256; }
  f32x4 acc3[2][2] = {};
  f16x8 ag[4][2];
  #pragma unroll
  for (int j = 0; j < 4; ++j) {
    ag[j][0] = *(const f16x8*)&wa3[(size_t)j * 8192];
    ag[j][1] = *(const f16x8*)&wa3[(size_t)j * 8192 + 128];
  }
  __syncthreads();   // h2T writes visible
  #pragma unroll 1
  for (int q = 0; q < 9; ++q) {             // quad of K-steps s=4q..4q+3 (kk=q)
    int q128 = q << 7;
    int qh = q >> 1;
    int i0[2];
    #pragma unroll
    for (int nn = 0; nn < 2; ++nn) {
      int t = (wn3[nn] + qh) & 15;
      i0[nn] = wn256[nn] + q128 + ((lg ^ t) << 3);  // j=0 (cc=lg)
    }
    #pragma unroll
    for (int j = 0; j < 4; ++j) {
      f16x8 bg[2];
      #pragma unroll
      for (int nn = 0; nn < 2; ++nn)
        bg[nn] = *(const f16x8*)&h2T[i0[nn] ^ (j << 5)];  // cc=j*4+lg -> ^(j*32) halves
      __builtin_amdgcn_s_setprio(1);
      #pragma unroll
      for (int mm = 0; mm < 2; ++mm)
        #pragma unroll
        for (int nn = 0; nn < 2; ++nn)
          acc3[mm][nn] = __builtin_amdgcn_mfma_f32_16x16x32_f16(ag[j][mm], bg[nn], acc3[mm][nn], 0, 0, 0);
      __builtin_amdgcn_s_setprio(0);
      if (q < 8) {
        const _Float16* wsrc = wa3 + (size_t)(4 * (q + 1) + j) * 8192;
        ag[j][0] = *(const f16x8*)&wsrc[0];
        ag[j][1] = *(const f16x8*)&wsrc[128];
      }
    }
  }
  // conv3 epilogue: BN+ReLU, masked partial w-sum, 16-lane reduce, then
  // pair-reduce the two w-half waves sharing each co chunk via LDS scratch.
  __syncthreads();   // all h2T reads done; reuse buf as f32 scratch
  {
    float* scratch = (float*)buf;            // 16 waves x 32 co = 512 f32
    const float* sc3 = scbi + 256;
    const float* bi3 = scbi + 512;
    #pragma unroll
    for (int mm = 0; mm < 2; ++mm) {
      #pragma unroll
      for (int r = 0; r < 4; ++r) {
        int cidx = mm * 16 + lg * 4 + r;     // 0..31 within cobase3
        float sc = sc3[cobase3 + cidx], bi = bi3[cobase3 + cidx];
        float sum = 0.f;
        #pragma unroll
        for (int nn = 0; nn < 2; ++nn) {
          float val = fmaxf(acc3[mm][nn][r] * sc + bi, 0.f);
          if (wn3[nn] < 60) sum += val;
        }
        sum += __shfl_xor(sum, 1);
        sum += __shfl_xor(sum, 2);
        sum += __shfl_xor(sum, 4);
        sum += __shfl_xor(sum, 8);
        if (lr == 0) scratch[wv * 32 + cidx] = sum;
      }
    }
    __syncthreads();
    if (tid < 256) {
      int p = tid >> 5, c = tid & 31;        // co = p*32 + c = tid
      part[(size_t)br * 256 + tid] = scratch[(2 * p) * 32 + c] + scratch[(2 * p + 1) * 32 + c];
    }
  }
}

// ---------------- K4a: Z = feat @ mw_in^T (feat computed in-block from part) ----------------
__global__ __launch_bounds__(256) void k4a_gemm_in(
    const _Float16* __restrict__ wInH, const float* __restrict__ part,
    float* __restrict__ Z) {
  __shared__ __align__(16) _Float16 featL[64][264];  // padded rows
  int tid = threadIdx.x;
  int mbase = blockIdx.x * 64, nbase = blockIdx.y * 64;
  for (int i = tid; i < 64 * 256; i += 256) {
    int b = i >> 8, c = i & 255;
    float s0 = part[((size_t)(nbase + b) * 2 + 0) * 256 + c];
    float s1 = part[((size_t)(nbase + b) * 2 + 1) * 256 + c];
    featL[b][c] = (_Float16)((s0 + s1) * (1.f / 120.f));
  }
  int l = tid & 63, wv = tid >> 6;
  int lr = l & 15, lg = l >> 4;
  int mo = (wv & 1) * 32, no = (wv >> 1) * 32;
  f32x4 acc[2][2] = {};
  __syncthreads();
  for (int s = 0; s < 8; ++s) {
    f16x8 af[2], bf[2];
    #pragma unroll
    for (int mm = 0; mm < 2; ++mm) {
      int row = mbase + mo + mm * 16 + lr;
      af[mm] = *(const f16x8*)&wInH[(size_t)row * 256 + s * 32 + lg * 8];
    }
    #pragma unroll
    for (int nn = 0; nn < 2; ++nn) {
      int b = no + nn * 16 + lr;
      bf[nn] = *(const f16x8*)&featL[b][s * 32 + lg * 8];
    }
    #pragma unroll
    for (int mm = 0; mm < 2; ++mm)
      #pragma unroll
      for (int nn = 0; nn < 2; ++nn)
        acc[mm][nn] = __builtin_amdgcn_mfma_f32_16x16x32_f16(af[mm], bf[nn], acc[mm][nn], 0, 0, 0);
  }
  #pragma unroll
  for (int mm = 0; mm < 2; ++mm) {
    int row0 = mbase + mo + mm * 16 + lg * 4;
    #pragma unroll
    for (int nn = 0; nn < 2; ++nn) {
      int b = nbase + no + nn * 16 + lr;
      *(float4*)&Z[(size_t)b * 1216 + row0] = *(float4*)&acc[mm][nn];
    }
  }
}

// ---------------- K4b: per-batch pointwise mamba core ----------------
__global__ __launch_bounds__(256) void k4b_pointwise(
    const float* __restrict__ Z,
    const float* __restrict__ mconv_w, const float* __restrict__ mconv_b,
    const float* __restrict__ mdt_bias, const float* __restrict__ mD,
    const float* __restrict__ mnorm_w, _Float16* __restrict__ yH) {
  __shared__ float zx[1160];
  __shared__ float red4[4];
  __shared__ float sBs;
  __shared__ float coef[8];
  int tid = threadIdx.x;
  int b = blockIdx.x;
  const float* zsrc = Z + (size_t)b * 1216;
  for (int row = tid; row < 1160; row += 256) zx[row] = zsrc[row];
  __syncthreads();
  for (int c = tid; c < 640; c += 256) {
    float t = zx[512 + c] * mconv_w[c * 4 + 3] + mconv_b[c];
    zx[512 + c] = t / (1.f + expf(-t));
  }
  __syncthreads();
  if (tid < 64) {
    float p = zx[1024 + tid] * zx[1088 + tid];
    #pragma unroll
    for (int off = 32; off > 0; off >>= 1) p += __shfl_xor(p, off, 64);
    if (tid == 0) sBs = p;
  }
  __syncthreads();
  if (tid < 8) {
    float u = zx[1152 + tid] + mdt_bias[tid];
    float sp = (u > 20.f) ? u : log1pf(expf(u));
    coef[tid] = sp * sBs + mD[tid];
  }
  __syncthreads();
  float ssq = 0.f;
  #pragma unroll
  for (int ii = 0; ii < 2; ++ii) {
    int i = tid + ii * 256;
    float z = zx[i];
    float t = zx[512 + i] * coef[i >> 6] * (z / (1.f + expf(-z)));
    zx[i] = t;
    ssq += t * t;
  }
  #pragma unroll
  for (int off = 32; off > 0; off >>= 1) ssq += __shfl_xor(ssq, off, 64);
  if ((tid & 63) == 0) red4[tid >> 6] = ssq;
  __syncthreads();
  {
    float total = red4[0] + red4[1] + red4[2] + red4[3];
    float rn = 1.f / sqrtf(total * (1.f / 512.f) + EPS);
    #pragma unroll
    for (int ii = 0; ii < 2; ++ii) {
      int i = tid + ii * 256;
      float y = zx[i] * rn * mnorm_w[i];
      yH[(size_t)b * 512 + i] = (_Float16)y;
    }
  }
}

// ---------------- K4c: ob = y @ mw_out^T as MFMA GEMM ----------------
__global__ __launch_bounds__(256) void k4c_gemm_out(
    const _Float16* __restrict__ wOutH, const _Float16* __restrict__ yH,
    _Float16* __restrict__ obH) {
  int tid = threadIdx.x;
  int mbase = blockIdx.x * 64, nbase = blockIdx.y * 64;
  int l = tid & 63, wv = tid >> 6;
  int lr = l & 15, lg = l >> 4;
  int mo = (wv & 1) * 32, no = (wv >> 1) * 32;
  f32x4 acc[2][2] = {};
  for (int s = 0; s < 16; ++s) {
    f16x8 af[2], bf[2];
    #pragma unroll
    for (int mm = 0; mm < 2; ++mm) {
      int row = mbase + mo + mm * 16 + lr;
      af[mm] = *(const f16x8*)&wOutH[(size_t)row * 512 + s * 32 + lg * 8];
    }
    #pragma unroll
    for (int nn = 0; nn < 2; ++nn) {
      int b = nbase + no + nn * 16 + lr;
      bf[nn] = *(const f16x8*)&yH[(size_t)b * 512 + s * 32 + lg * 8];
    }
    #pragma unroll
    for (int mm = 0; mm < 2; ++mm)
      #pragma unroll
      for (int nn = 0; nn < 2; ++nn)
        acc[mm][nn] = __builtin_amdgcn_mfma_f32_16x16x32_f16(af[mm], bf[nn], acc[mm][nn], 0, 0, 0);
  }
  #pragma unroll
  for (int mm = 0; mm < 2; ++mm) {
    int row0 = mbase + mo + mm * 16 + lg * 4;
    #pragma unroll
    for (int nn = 0; nn < 2; ++nn) {
      int b = nbase + no + nn * 16 + lr;
      f16x4 hv;
      hv[0] = (_Float16)acc[mm][nn][0];
      hv[1] = (_Float16)acc[mm][nn][1];
      hv[2] = (_Float16)acc[mm][nn][2];
      hv[3] = (_Float16)acc[mm][nn][3];
      *(f16x4*)&obH[(size_t)b * 256 + row0] = hv;
    }
  }
}

// ---------------- K4d: head ----------------
__global__ __launch_bounds__(256) void k4d_head(
    const _Float16* __restrict__ f1H, const _Float16* __restrict__ obH,
    const float* __restrict__ scbi, const float* __restrict__ f2w,
    const float* __restrict__ f2b, float* __restrict__ outp) {
  int tid = threadIdx.x;
  int nbase = blockIdx.x * 64;
  int l = tid & 63, wv = tid >> 6;
  int lr = l & 15, lg = l >> 4;
  int bcol = nbase + wv * 16 + lr;
  f32x4 acc[4] = {};
  for (int s = 0; s < 8; ++s) {
    f16x8 bf = *(const f16x8*)&obH[(size_t)bcol * 256 + s * 32 + lg * 8];
    #pragma unroll
    for (int mm = 0; mm < 4; ++mm) {
      f16x8 af = *(const f16x8*)&f1H[(size_t)(mm * 16 + lr) * 256 + s * 32 + lg * 8];
      acc[mm] = __builtin_amdgcn_mfma_f32_16x16x32_f16(af, bf, acc[mm], 0, 0, 0);
    }
  }
  float psum = 0.f;
  #pragma unroll
  for (int mm = 0; mm < 4; ++mm) {
    #pragma unroll
    for (int r = 0; r < 4; ++r) {
      int row = mm * 16 + lg * 4 + r;
      float val = acc[mm][r] * scbi[768 + row] + scbi[832 + row];
      val = fmaxf(val, 0.f);
      psum += val * f2w[row];
    }
  }
  psum += __shfl_xor(psum, 16, 64);
  psum += __shfl_xor(psum, 32, 64);
  if (l < 16) outp[bcol] = psum + f2b[0];
}

extern "C" void kernel_launch(void* const* d_in, const int* in_sizes, int n_in,
                              void* d_out, int out_size, void* d_ws, size_t ws_size,
                              hipStream_t stream) {
  const float* x    = (const float*)d_in[0];
  const float* c1w  = (const float*)d_in[1];
  const float* c1b  = (const float*)d_in[2];
  const float* bn1g = (const float*)d_in[3];
  const float* bn1b = (const float*)d_in[4];
  const float* bn1m = (const float*)d_in[5];
  const float* bn1v = (const float*)d_in[6];
  const float* c2w  = (const float*)d_in[7];
  const float* c2b  = (const float*)d_in[8];
  const float* bn2g = (const float*)d_in[9];
  const float* bn2b = (const float*)d_in[10];
  const float* bn2m = (const float*)d_in[11];
  const float* bn2v = (const float*)d_in[12];
  const float* c3w  = (const float*)d_in[13];
  const float* c3b  = (const float*)d_in[14];
  const float* bn3g = (const float*)d_in[15];
  const float* bn3b = (const float*)d_in[16];
  const float* bn3m = (const float*)d_in[17];
  const float* bn3v = (const float*)d_in[18];
  const float* mw_in    = (const float*)d_in[19];
  const float* mconv_w  = (const float*)d_in[20];
  const float* mconv_b  = (const float*)d_in[21];
  const float* mdt_bias = (const float*)d_in[22];
  // d_in[23] = mA_log: unused (L=1 scan from h0=0 makes dA dead)
  const float* mD       = (const float*)d_in[24];
  const float* mnorm_w  = (const float*)d_in[25];
  const float* mw_out   = (const float*)d_in[26];
  const float* f1w  = (const float*)d_in[27];
  const float* f1b  = (const float*)d_in[28];
  const float* bn4g = (const float*)d_in[29];
  const float* bn4b = (const float*)d_in[30];
  const float* bn4m = (const float*)d_in[31];
  const float* bn4v = (const float*)d_in[32];
  const float* f2w  = (const float*)d_in[33];
  const float* f2b  = (const float*)d_in[34];

  _Float16* p1h   = (_Float16*)d_ws;             // unused after k123 fusion (layout stability)
  _Float16* h2h   = p1h + (size_t)512 * 18432;   // unused
  _Float16* wA2h  = h2h + (size_t)512 * 18432;
  _Float16* wA3h  = wA2h + 172032;
  _Float16* wInH  = wA3h + 294912;
  _Float16* wOutH = wInH + (size_t)1216 * 256;
  _Float16* f1H   = wOutH + (size_t)256 * 512;
  _Float16* featH = f1H + 64 * 256;              // unused
  _Float16* yH    = featH + 256 * 256;
  _Float16* obH   = yH + (size_t)256 * 512;
  _Float16* wA1h  = obH + 256 * 256;
  float*    scbi  = (float*)(wA1h + 4096);
  float*    part  = scbi + 1024;
  float*    Z     = part + (size_t)512 * 256;
  float*    outp  = (float*)d_out;

  k0_prep<<<dim3(512), dim3(256), 0, stream>>>(c2w, c3w, c2b, bn2g, bn2b, bn2m, bn2v,
                                               c3b, bn3g, bn3b, bn3m, bn3v,
                                               mw_in, mw_out, f1w, f1b, bn4g, bn4b, bn4m, bn4v,
                                               c1w, c1b, bn1g, bn1b, bn1m, bn1v,
                                               wA2h, wA3h, wInH, wOutH, f1H, wA1h, scbi);
  k123_conv123<<<dim3(512), dim3(1024), 0, stream>>>(x, wA1h, wA2h, wA3h, scbi, part);
  k4a_gemm_in<<<dim3(19, 4), dim3(256), 0, stream>>>(wInH, part, Z);
  k4b_pointwise<<<dim3(256), dim3(256), 0, stream>>>(Z, mconv_w, mconv_b, mdt_bias, mD, mnorm_w, yH);
  k4c_gemm_out<<<dim3(4, 4), dim3(256), 0, stream>>>(wOutH, yH, obH);
  k4d_head<<<dim3(4), dim3(256), 0, stream>>>(f1H, obH, scbi, f2w, f2b, outp);
}

// Round 7
// 101.046 us; speedup vs baseline: 1.6892x; 1.6892x over previous
//
#include <hip/hip_runtime.h>
#include <math.h>

#define EPS 1e-5f

typedef _Float16 f16x8 __attribute__((ext_vector_type(8)));
typedef _Float16 f16x4 __attribute__((ext_vector_type(4)));
typedef float    f32x4 __attribute__((ext_vector_type(4)));

// ---------------- K0: weight packing + BN coefficient prep ----------------
__global__ void k0_prep(const float* __restrict__ c2w, const float* __restrict__ c3w,
                        const float* __restrict__ c2b, const float* __restrict__ bn2g,
                        const float* __restrict__ bn2b, const float* __restrict__ bn2m,
                        const float* __restrict__ bn2v,
                        const float* __restrict__ c3b, const float* __restrict__ bn3g,
                        const float* __restrict__ bn3b, const float* __restrict__ bn3m,
                        const float* __restrict__ bn3v,
                        const float* __restrict__ mw_in, const float* __restrict__ mw_out,
                        const float* __restrict__ f1w, const float* __restrict__ f1b,
                        const float* __restrict__ bn4g, const float* __restrict__ bn4b,
                        const float* __restrict__ bn4m, const float* __restrict__ bn4v,
                        const float* __restrict__ c1w, const float* __restrict__ c1b,
                        const float* __restrict__ bn1g, const float* __restrict__ bn1b,
                        const float* __restrict__ bn1m, const float* __restrict__ bn1v,
                        _Float16* __restrict__ wA2h, _Float16* __restrict__ wA3h,
                        _Float16* __restrict__ wInH, _Float16* __restrict__ wOutH,
                        _Float16* __restrict__ f1H, _Float16* __restrict__ wA1h,
                        float* __restrict__ scbi) {
  int idx = blockIdx.x * blockDim.x + threadIdx.x;
  int stride = gridDim.x * blockDim.x;
  for (int i = idx; i < 172032; i += stride) {
    int j = i & 7; int t = i >> 3; int co = t & 127; int sg = t >> 7;
    int kglob = sg * 8 + j;
    int ci = kglob & 63, kk = kglob >> 6;
    wA2h[i] = (_Float16)c2w[(co * 64 + ci) * 21 + kk];
  }
  for (int i = idx; i < 294912; i += stride) {
    int j = i & 7; int t = i >> 3; int co = t & 255; int sg = t >> 8;
    int kglob = sg * 8 + j;
    int ci = kglob & 127, kk = kglob >> 7;
    wA3h[i] = (_Float16)c3w[(co * 128 + ci) * 9 + kk];
  }
  for (int i = idx; i < 1216 * 256; i += stride) {
    int row = i >> 8;
    wInH[i] = (row < 1160) ? (_Float16)mw_in[i] : (_Float16)0.f;
  }
  for (int i = idx; i < 256 * 512; i += stride) wOutH[i] = (_Float16)mw_out[i];
  for (int i = idx; i < 64 * 256; i += stride)  f1H[i]  = (_Float16)f1w[i];
  for (int i = idx; i < 4096; i += stride) {
    int kglob = i & 63, co = i >> 6;
    int r = kglob >> 4, q = kglob & 15;
    int k = 4 * q + r;
    wA1h[i] = (k < 51) ? (_Float16)c1w[co * 51 + k] : (_Float16)0.f;
  }
  if (idx < 128) {
    float sc = bn2g[idx] / sqrtf(bn2v[idx] + EPS);
    scbi[idx] = sc;
    scbi[128 + idx] = (c2b[idx] - bn2m[idx]) * sc + bn2b[idx];
  }
  if (idx < 256) {
    float sc = bn3g[idx] / sqrtf(bn3v[idx] + EPS);
    scbi[256 + idx] = sc;
    scbi[512 + idx] = (c3b[idx] - bn3m[idx]) * sc + bn3b[idx];
  }
  if (idx < 64) {
    float sc = bn4g[idx] / sqrtf(bn4v[idx] + EPS);
    scbi[768 + idx] = sc;
    scbi[832 + idx] = (f1b[idx] - bn4m[idx]) * sc + bn4b[idx];
  }
  if (idx >= 64 && idx < 128) {
    int c = idx - 64;
    float sc = bn1g[c] / sqrtf(bn1v[c] + EPS);
    scbi[896 + c] = sc;
    scbi[960 + c] = (c1b[c] - bn1m[c]) * sc + bn1b[c];
  }
}

// ---------------- K123: fused conv1+pool -> conv2 -> conv3 -> w-mean ----------------
// R7: 16-wave occupancy retry with the register diet done right. R6's
// spill (FETCH 194MB, VGPR forced to 32) came from conv1's mm=4 phase
// (~90 VGPR) vs the 64-VGPR budget of 8 waves/SIMD. Fixes: (1) conv1
// split mm=2 across co-halves (wave = co-half wv&1, w-group wv>>1;
// ~58 VGPR); (2) conv3 A-prefetch 2-deep ping-pong agA/agB (saves 16
// VGPR; distance 2 clusters is enough -- 8 waves/SIMD TLP hides L2 now).
// conv2 + epilogues + scratch pair-reduce identical to R6 (correctness
// was verified there). Pass signal: VGPR=64, FETCH ~7.6MB. Fail signal:
// FETCH >> 10MB (spill) -> revert to R5, declare structural limit.
__global__ __launch_bounds__(1024, 8) void k123_conv123(
    const float* __restrict__ x, const _Float16* __restrict__ wA1h,
    const _Float16* __restrict__ wA2h, const _Float16* __restrict__ wA3h,
    const float* __restrict__ scbi, float* __restrict__ part) {
  __shared__ float phx[4 * 980];                 // conv1 phase arrays x_r[t]
  __shared__ __align__(16) _Float16 buf[18432];  // xT [288][64] -> h2T [144][128] -> f32 scratch
  _Float16* xT  = buf;
  _Float16* h2T = buf;
  int br = blockIdx.x, tid = threadIdx.x;
  // ---- stage: zero phx and xT pad rows ----
  for (int i = tid; i < 3920; i += 1024) phx[i] = 0.f;
  {
    float4 z4 = make_float4(0.f, 0.f, 0.f, 0.f);
    for (int i = tid; i < 80; i += 1024)  ((float4*)xT)[i] = z4;            // rows 0..9
    for (int i = tid; i < 304; i += 1024) ((float4*)(xT + 16000))[i] = z4;  // rows 250..287
  }
  __syncthreads();
  const float* xrow = x + (size_t)br * 3840;
  for (int i = tid; i < 960; i += 1024) {
    float4 v = ((const float4*)xrow)[i];
    int g = 4 * i;
    #pragma unroll
    for (int c = 0; c < 4; ++c) {
      int gp = g + c + 25;                 // = 4t + r
      phx[(gp & 3) * 980 + (gp >> 2)] = ((const float*)&v)[c];
    }
  }
  int l = tid & 63, wv = tid >> 6;      // wv 0..15
  int lr = l & 15, lg = l >> 4;
  // ---- conv1 phase: 16 waves = (co half ch=wv&1) x (w-group gq=wv>>1 + 8*it) ----
  {
    int ch = wv & 1, gq = wv >> 1;
    f16x8 af1[2][2];
    #pragma unroll
    for (int s = 0; s < 2; ++s)
      #pragma unroll
      for (int mm = 0; mm < 2; ++mm)
        af1[s][mm] = *(const f16x8*)&wA1h[(ch * 32 + mm * 16 + lr) * 64 + s * 32 + lg * 8];
    float scr[2][4], bir[2][4];
    #pragma unroll
    for (int mm = 0; mm < 2; ++mm)
      #pragma unroll
      for (int r2 = 0; r2 < 4; ++r2) {
        int co = ch * 32 + mm * 16 + lg * 4 + r2;
        scr[mm][r2] = scbi[896 + co];
        bir[mm][r2] = scbi[960 + co];
      }
    __syncthreads();   // phx + pad zeros visible
    for (int it = 0; it < 8; ++it) {
      int g = gq + 8 * it;
      if (g < 60) {
        int w0 = g * 16;
        f32x4 acc1[2] = {};
        #pragma unroll
        for (int s = 0; s < 2; ++s) {
          int r = s * 2 + (lg >> 1), q0 = (lg & 1) * 8;
          const float* src = &phx[r * 980 + w0 + lr + q0];
          f16x8 bf;
          #pragma unroll
          for (int j = 0; j < 8; ++j) bf[j] = (_Float16)src[j];
          #pragma unroll
          for (int mm = 0; mm < 2; ++mm)
            acc1[mm] = __builtin_amdgcn_mfma_f32_16x16x32_f16(af1[s][mm], bf, acc1[mm], 0, 0, 0);
        }
        int pp = w0 / 4 + (lr >> 2);       // pooled index 0..239
        int p = pp + 10;                   // xT row
        int cpx = (p >> 1) & 7;
        #pragma unroll
        for (int mm = 0; mm < 2; ++mm) {
          int co0 = ch * 32 + mm * 16 + lg * 4;
          f16x4 hv;
          #pragma unroll
          for (int r2 = 0; r2 < 4; ++r2) {
            float v0 = acc1[mm][r2] * scr[mm][r2] + bir[mm][r2];
            float m1 = fmaxf(v0, __shfl_xor(v0, 1));
            float m2 = fmaxf(m1, __shfl_xor(m1, 2));
            hv[r2] = (_Float16)fmaxf(m2, 0.f);
          }
          if ((lr & 3) == 0)
            *(f16x4*)&xT[p * 64 + ((co0 >> 3) ^ cpx) * 8 + (co0 & 7)] = hv;
        }
      }
    }
  }
  // ---- conv2 phase: wave = (co group of 32: wv>>2) x (w quarter of 32: wv&3) ----
  int cobase = (wv >> 2) * 32, wbase = (wv & 3) * 32;
  int arow2 = lg * 128 + cobase + lr;
  int wn[2], wn128[2];
  #pragma unroll
  for (int nn = 0; nn < 2; ++nn) { wn[nn] = wbase + nn * 16 + lr; wn128[nn] = wn[nn] * 128; }
  f32x4 acc[2][2] = {};
  const _Float16* wa2 = wA2h + (size_t)arow2 * 8;   // step s at wa2[s*4096 + mm*128]
  f16x8 afE[2], afO[2];
  afE[0] = *(const f16x8*)&wa2[0];
  afE[1] = *(const f16x8*)&wa2[128];
  afO[0] = *(const f16x8*)&wa2[4096];
  afO[1] = *(const f16x8*)&wa2[4096 + 128];
  __syncthreads();   // xT fully written
  #pragma unroll 1
  for (int sp = 0; sp < 21; ++sp) {         // pair of K-steps s=2sp, 2sp+1 (kk=sp for both)
    int sp64 = sp * 64;
    int sph = sp >> 1;
    f16x8 bf0[2], bf1[2];
    #pragma unroll
    for (int nn = 0; nn < 2; ++nn) {
      int t = (wn[nn] + sph) & 7;
      int i0 = wn128[nn] + sp64 + ((lg ^ t) << 3);  // half-index; even step (cc=lg)
      bf0[nn] = *(const f16x8*)&xT[i0];
      bf1[nn] = *(const f16x8*)&xT[i0 ^ 32];        // odd step: cc=4+lg -> ^32 halves
    }
    __builtin_amdgcn_s_setprio(1);
    #pragma unroll
    for (int mm = 0; mm < 2; ++mm)
      #pragma unroll
      for (int nn = 0; nn < 2; ++nn)
        acc[mm][nn] = __builtin_amdgcn_mfma_f32_16x16x32_f16(afE[mm], bf0[nn], acc[mm][nn], 0, 0, 0);
    __builtin_amdgcn_s_setprio(0);
    if (sp < 20) {
      const _Float16* wsrc = wa2 + (size_t)(2 * sp + 2) * 4096;
      afE[0] = *(const f16x8*)&wsrc[0];
      afE[1] = *(const f16x8*)&wsrc[128];
    }
    __builtin_amdgcn_s_setprio(1);
    #pragma unroll
    for (int mm = 0; mm < 2; ++mm)
      #pragma unroll
      for (int nn = 0; nn < 2; ++nn)
        acc[mm][nn] = __builtin_amdgcn_mfma_f32_16x16x32_f16(afO[mm], bf1[nn], acc[mm][nn], 0, 0, 0);
    __builtin_amdgcn_s_setprio(0);
    if (sp < 20) {
      const _Float16* wsrc = wa2 + (size_t)(2 * sp + 3) * 4096;
      afO[0] = *(const f16x8*)&wsrc[0];
      afO[1] = *(const f16x8*)&wsrc[128];
    }
  }
  __syncthreads();   // all xT reads done; buf may now be overwritten as h2T
  // conv2 epilogue: BN+ReLU -> h2T (aliased buf), plus pad-row zeroing
  {
    float4 z4 = make_float4(0.f, 0.f, 0.f, 0.f);
    for (int i = tid; i < 384; i += 1024) {
      int h8 = (i < 64) ? i : (1984 + (i - 64));
      *(float4*)&h2T[h8 * 8] = z4;
    }
    const float* sc2 = scbi;
    const float* bi2 = scbi + 128;
    #pragma unroll
    for (int mm = 0; mm < 2; ++mm) {
      int co0 = cobase + mm * 16 + lg * 4;
      float s0 = sc2[co0], s1 = sc2[co0 + 1], s2 = sc2[co0 + 2], s3 = sc2[co0 + 3];
      float b0 = bi2[co0], b1 = bi2[co0 + 1], b2 = bi2[co0 + 2], b3 = bi2[co0 + 3];
      #pragma unroll
      for (int nn = 0; nn < 2; ++nn) {
        int w = wn[nn];
        if (w < 120) {
          int p3 = 4 + w;
          f16x4 hv;
          hv[0] = (_Float16)fmaxf(acc[mm][nn][0] * s0 + b0, 0.f);
          hv[1] = (_Float16)fmaxf(acc[mm][nn][1] * s1 + b1, 0.f);
          hv[2] = (_Float16)fmaxf(acc[mm][nn][2] * s2 + b2, 0.f);
          hv[3] = (_Float16)fmaxf(acc[mm][nn][3] * s3 + b3, 0.f);
          int cp = (co0 >> 3) ^ ((p3 >> 1) & 15);
          *(f16x4*)&h2T[p3 * 128 + cp * 8 + (co0 & 7)] = hv;
        }
      }
    }
  }
  // ---- conv3 phase: wave = (co chunk of 32: wv>>1) x (w half of 32: wv&1) ----
  int cobase3 = (wv >> 1) * 32, wbase3 = (wv & 1) * 32;
  int arow3 = lg * 256 + cobase3 + lr;
  const _Float16* wa3 = wA3h + (size_t)arow3 * 8;   // step s at wa3[s*8192 + mm*128]
  int wn3[2], wn256[2];
  #pragma unroll
  for (int nn = 0; nn < 2; ++nn) { wn3[nn] = wbase3 + nn * 16 + lr; wn256[nn] = wn3[nn] * 256; }
  f32x4 acc3[2][2] = {};
  f16x8 agA[2], agB[2];                 // 2-deep ping-pong: agA even s, agB odd s
  agA[0] = *(const f16x8*)&wa3[0];
  agA[1] = *(const f16x8*)&wa3[128];
  agB[0] = *(const f16x8*)&wa3[8192];
  agB[1] = *(const f16x8*)&wa3[8192 + 128];
  __syncthreads();   // h2T writes visible
  #pragma unroll 1
  for (int q = 0; q < 9; ++q) {             // quad of K-steps s=4q..4q+3 (kk=q)
    int q128 = q << 7;
    int qh = q >> 1;
    int i0[2];
    #pragma unroll
    for (int nn = 0; nn < 2; ++nn) {
      int t = (wn3[nn] + qh) & 15;
      i0[nn] = wn256[nn] + q128 + ((lg ^ t) << 3);  // j=0 (cc=lg)
    }
    #pragma unroll
    for (int j = 0; j < 4; ++j) {
      f16x8 bg[2];
      #pragma unroll
      for (int nn = 0; nn < 2; ++nn)
        bg[nn] = *(const f16x8*)&h2T[i0[nn] ^ (j << 5)];  // cc=j*4+lg -> ^(j*32) halves
      __builtin_amdgcn_s_setprio(1);
      if ((j & 1) == 0) {
        #pragma unroll
        for (int mm = 0; mm < 2; ++mm)
          #pragma unroll
          for (int nn = 0; nn < 2; ++nn)
            acc3[mm][nn] = __builtin_amdgcn_mfma_f32_16x16x32_f16(agA[mm], bg[nn], acc3[mm][nn], 0, 0, 0);
      } else {
        #pragma unroll
        for (int mm = 0; mm < 2; ++mm)
          #pragma unroll
          for (int nn = 0; nn < 2; ++nn)
            acc3[mm][nn] = __builtin_amdgcn_mfma_f32_16x16x32_f16(agB[mm], bg[nn], acc3[mm][nn], 0, 0, 0);
      }
      __builtin_amdgcn_s_setprio(0);
      int snext = 4 * q + j + 2;            // refill the slot just consumed
      if (snext < 36) {
        const _Float16* wsrc = wa3 + (size_t)snext * 8192;
        if ((j & 1) == 0) {
          agA[0] = *(const f16x8*)&wsrc[0];
          agA[1] = *(const f16x8*)&wsrc[128];
        } else {
          agB[0] = *(const f16x8*)&wsrc[0];
          agB[1] = *(const f16x8*)&wsrc[128];
        }
      }
    }
  }
  // conv3 epilogue: BN+ReLU, masked partial w-sum, 16-lane reduce, then
  // pair-reduce the two w-half waves sharing each co chunk via LDS scratch.
  __syncthreads();   // all h2T reads done; reuse buf as f32 scratch
  {
    float* scratch = (float*)buf;            // 16 waves x 32 co = 512 f32
    const float* sc3 = scbi + 256;
    const float* bi3 = scbi + 512;
    #pragma unroll
    for (int mm = 0; mm < 2; ++mm) {
      #pragma unroll
      for (int r = 0; r < 4; ++r) {
        int cidx = mm * 16 + lg * 4 + r;     // 0..31 within cobase3
        float sc = sc3[cobase3 + cidx], bi = bi3[cobase3 + cidx];
        float sum = 0.f;
        #pragma unroll
        for (int nn = 0; nn < 2; ++nn) {
          float val = fmaxf(acc3[mm][nn][r] * sc + bi, 0.f);
          if (wn3[nn] < 60) sum += val;
        }
        sum += __shfl_xor(sum, 1);
        sum += __shfl_xor(sum, 2);
        sum += __shfl_xor(sum, 4);
        sum += __shfl_xor(sum, 8);
        if (lr == 0) scratch[wv * 32 + cidx] = sum;
      }
    }
    __syncthreads();
    if (tid < 256) {
      int p = tid >> 5, c = tid & 31;        // co = p*32 + c = tid
      part[(size_t)br * 256 + tid] = scratch[(2 * p) * 32 + c] + scratch[(2 * p + 1) * 32 + c];
    }
  }
}

// ---------------- K4a: Z = feat @ mw_in^T (feat computed in-block from part) ----------------
__global__ __launch_bounds__(256) void k4a_gemm_in(
    const _Float16* __restrict__ wInH, const float* __restrict__ part,
    float* __restrict__ Z) {
  __shared__ __align__(16) _Float16 featL[64][264];  // padded rows
  int tid = threadIdx.x;
  int mbase = blockIdx.x * 64, nbase = blockIdx.y * 64;
  for (int i = tid; i < 64 * 256; i += 256) {
    int b = i >> 8, c = i & 255;
    float s0 = part[((size_t)(nbase + b) * 2 + 0) * 256 + c];
    float s1 = part[((size_t)(nbase + b) * 2 + 1) * 256 + c];
    featL[b][c] = (_Float16)((s0 + s1) * (1.f / 120.f));
  }
  int l = tid & 63, wv = tid >> 6;
  int lr = l & 15, lg = l >> 4;
  int mo = (wv & 1) * 32, no = (wv >> 1) * 32;
  f32x4 acc[2][2] = {};
  __syncthreads();
  for (int s = 0; s < 8; ++s) {
    f16x8 af[2], bf[2];
    #pragma unroll
    for (int mm = 0; mm < 2; ++mm) {
      int row = mbase + mo + mm * 16 + lr;
      af[mm] = *(const f16x8*)&wInH[(size_t)row * 256 + s * 32 + lg * 8];
    }
    #pragma unroll
    for (int nn = 0; nn < 2; ++nn) {
      int b = no + nn * 16 + lr;
      bf[nn] = *(const f16x8*)&featL[b][s * 32 + lg * 8];
    }
    #pragma unroll
    for (int mm = 0; mm < 2; ++mm)
      #pragma unroll
      for (int nn = 0; nn < 2; ++nn)
        acc[mm][nn] = __builtin_amdgcn_mfma_f32_16x16x32_f16(af[mm], bf[nn], acc[mm][nn], 0, 0, 0);
  }
  #pragma unroll
  for (int mm = 0; mm < 2; ++mm) {
    int row0 = mbase + mo + mm * 16 + lg * 4;
    #pragma unroll
    for (int nn = 0; nn < 2; ++nn) {
      int b = nbase + no + nn * 16 + lr;
      *(float4*)&Z[(size_t)b * 1216 + row0] = *(float4*)&acc[mm][nn];
    }
  }
}

// ---------------- K4b: per-batch pointwise mamba core ----------------
__global__ __launch_bounds__(256) void k4b_pointwise(
    const float* __restrict__ Z,
    const float* __restrict__ mconv_w, const float* __restrict__ mconv_b,
    const float* __restrict__ mdt_bias, const float* __restrict__ mD,
    const float* __restrict__ mnorm_w, _Float16* __restrict__ yH) {
  __shared__ float zx[1160];
  __shared__ float red4[4];
  __shared__ float sBs;
  __shared__ float coef[8];
  int tid = threadIdx.x;
  int b = blockIdx.x;
  const float* zsrc = Z + (size_t)b * 1216;
  for (int row = tid; row < 1160; row += 256) zx[row] = zsrc[row];
  __syncthreads();
  for (int c = tid; c < 640; c += 256) {
    float t = zx[512 + c] * mconv_w[c * 4 + 3] + mconv_b[c];
    zx[512 + c] = t / (1.f + expf(-t));
  }
  __syncthreads();
  if (tid < 64) {
    float p = zx[1024 + tid] * zx[1088 + tid];
    #pragma unroll
    for (int off = 32; off > 0; off >>= 1) p += __shfl_xor(p, off, 64);
    if (tid == 0) sBs = p;
  }
  __syncthreads();
  if (tid < 8) {
    float u = zx[1152 + tid] + mdt_bias[tid];
    float sp = (u > 20.f) ? u : log1pf(expf(u));
    coef[tid] = sp * sBs + mD[tid];
  }
  __syncthreads();
  float ssq = 0.f;
  #pragma unroll
  for (int ii = 0; ii < 2; ++ii) {
    int i = tid + ii * 256;
    float z = zx[i];
    float t = zx[512 + i] * coef[i >> 6] * (z / (1.f + expf(-z)));
    zx[i] = t;
    ssq += t * t;
  }
  #pragma unroll
  for (int off = 32; off > 0; off >>= 1) ssq += __shfl_xor(ssq, off, 64);
  if ((tid & 63) == 0) red4[tid >> 6] = ssq;
  __syncthreads();
  {
    float total = red4[0] + red4[1] + red4[2] + red4[3];
    float rn = 1.f / sqrtf(total * (1.f / 512.f) + EPS);
    #pragma unroll
    for (int ii = 0; ii < 2; ++ii) {
      int i = tid + ii * 256;
      float y = zx[i] * rn * mnorm_w[i];
      yH[(size_t)b * 512 + i] = (_Float16)y;
    }
  }
}

// ---------------- K4c: ob = y @ mw_out^T as MFMA GEMM ----------------
__global__ __launch_bounds__(256) void k4c_gemm_out(
    const _Float16* __restrict__ wOutH, const _Float16* __restrict__ yH,
    _Float16* __restrict__ obH) {
  int tid = threadIdx.x;
  int mbase = blockIdx.x * 64, nbase = blockIdx.y * 64;
  int l = tid & 63, wv = tid >> 6;
  int lr = l & 15, lg = l >> 4;
  int mo = (wv & 1) * 32, no = (wv >> 1) * 32;
  f32x4 acc[2][2] = {};
  for (int s = 0; s < 16; ++s) {
    f16x8 af[2], bf[2];
    #pragma unroll
    for (int mm = 0; mm < 2; ++mm) {
      int row = mbase + mo + mm * 16 + lr;
      af[mm] = *(const f16x8*)&wOutH[(size_t)row * 512 + s * 32 + lg * 8];
    }
    #pragma unroll
    for (int nn = 0; nn < 2; ++nn) {
      int b = nbase + no + nn * 16 + lr;
      bf[nn] = *(const f16x8*)&yH[(size_t)b * 512 + s * 32 + lg * 8];
    }
    #pragma unroll
    for (int mm = 0; mm < 2; ++mm)
      #pragma unroll
      for (int nn = 0; nn < 2; ++nn)
        acc[mm][nn] = __builtin_amdgcn_mfma_f32_16x16x32_f16(af[mm], bf[nn], acc[mm][nn], 0, 0, 0);
  }
  #pragma unroll
  for (int mm = 0; mm < 2; ++mm) {
    int row0 = mbase + mo + mm * 16 + lg * 4;
    #pragma unroll
    for (int nn = 0; nn < 2; ++nn) {
      int b = nbase + no + nn * 16 + lr;
      f16x4 hv;
      hv[0] = (_Float16)acc[mm][nn][0];
      hv[1] = (_Float16)acc[mm][nn][1];
      hv[2] = (_Float16)acc[mm][nn][2];
      hv[3] = (_Float16)acc[mm][nn][3];
      *(f16x4*)&obH[(size_t)b * 256 + row0] = hv;
    }
  }
}

// ---------------- K4d: head ----------------
__global__ __launch_bounds__(256) void k4d_head(
    const _Float16* __restrict__ f1H, const _Float16* __restrict__ obH,
    const float* __restrict__ scbi, const float* __restrict__ f2w,
    const float* __restrict__ f2b, float* __restrict__ outp) {
  int tid = threadIdx.x;
  int nbase = blockIdx.x * 64;
  int l = tid & 63, wv = tid >> 6;
  int lr = l & 15, lg = l >> 4;
  int bcol = nbase + wv * 16 + lr;
  f32x4 acc[4] = {};
  for (int s = 0; s < 8; ++s) {
    f16x8 bf = *(const f16x8*)&obH[(size_t)bcol * 256 + s * 32 + lg * 8];
    #pragma unroll
    for (int mm = 0; mm < 4; ++mm) {
      f16x8 af = *(const f16x8*)&f1H[(size_t)(mm * 16 + lr) * 256 + s * 32 + lg * 8];
      acc[mm] = __builtin_amdgcn_mfma_f32_16x16x32_f16(af, bf, acc[mm], 0, 0, 0);
    }
  }
  float psum = 0.f;
  #pragma unroll
  for (int mm = 0; mm < 4; ++mm) {
    #pragma unroll
    for (int r = 0; r < 4; ++r) {
      int row = mm * 16 + lg * 4 + r;
      float val = acc[mm][r] * scbi[768 + row] + scbi[832 + row];
      val = fmaxf(val, 0.f);
      psum += val * f2w[row];
    }
  }
  psum += __shfl_xor(psum, 16, 64);
  psum += __shfl_xor(psum, 32, 64);
  if (l < 16) outp[bcol] = psum + f2b[0];
}

extern "C" void kernel_launch(void* const* d_in, const int* in_sizes, int n_in,
                              void* d_out, int out_size, void* d_ws, size_t ws_size,
                              hipStream_t stream) {
  const float* x    = (const float*)d_in[0];
  const float* c1w  = (const float*)d_in[1];
  const float* c1b  = (const float*)d_in[2];
  const float* bn1g = (const float*)d_in[3];
  const float* bn1b = (const float*)d_in[4];
  const float* bn1m = (const float*)d_in[5];
  const float* bn1v = (const float*)d_in[6];
  const float* c2w  = (const float*)d_in[7];
  const float* c2b  = (const float*)d_in[8];
  const float* bn2g = (const float*)d_in[9];
  const float* bn2b = (const float*)d_in[10];
  const float* bn2m = (const float*)d_in[11];
  const float* bn2v = (const float*)d_in[12];
  const float* c3w  = (const float*)d_in[13];
  const float* c3b  = (const float*)d_in[14];
  const float* bn3g = (const float*)d_in[15];
  const float* bn3b = (const float*)d_in[16];
  const float* bn3m = (const float*)d_in[17];
  const float* bn3v = (const float*)d_in[18];
  const float* mw_in    = (const float*)d_in[19];
  const float* mconv_w  = (const float*)d_in[20];
  const float* mconv_b  = (const float*)d_in[21];
  const float* mdt_bias = (const float*)d_in[22];
  // d_in[23] = mA_log: unused (L=1 scan from h0=0 makes dA dead)
  const float* mD       = (const float*)d_in[24];
  const float* mnorm_w  = (const float*)d_in[25];
  const float* mw_out   = (const float*)d_in[26];
  const float* f1w  = (const float*)d_in[27];
  const float* f1b  = (const float*)d_in[28];
  const float* bn4g = (const float*)d_in[29];
  const float* bn4b = (const float*)d_in[30];
  const float* bn4m = (const float*)d_in[31];
  const float* bn4v = (const float*)d_in[32];
  const float* f2w  = (const float*)d_in[33];
  const float* f2b  = (const float*)d_in[34];

  _Float16* p1h   = (_Float16*)d_ws;             // unused after k123 fusion (layout stability)
  _Float16* h2h   = p1h + (size_t)512 * 18432;   // unused
  _Float16* wA2h  = h2h + (size_t)512 * 18432;
  _Float16* wA3h  = wA2h + 172032;
  _Float16* wInH  = wA3h + 294912;
  _Float16* wOutH = wInH + (size_t)1216 * 256;
  _Float16* f1H   = wOutH + (size_t)256 * 512;
  _Float16* featH = f1H + 64 * 256;              // unused
  _Float16* yH    = featH + 256 * 256;
  _Float16* obH   = yH + (size_t)256 * 512;
  _Float16* wA1h  = obH + 256 * 256;
  float*    scbi  = (float*)(wA1h + 4096);
  float*    part  = scbi + 1024;
  float*    Z     = part + (size_t)512 * 256;
  float*    outp  = (float*)d_out;

  k0_prep<<<dim3(512), dim3(256), 0, stream>>>(c2w, c3w, c2b, bn2g, bn2b, bn2m, bn2v,
                                               c3b, bn3g, bn3b, bn3m, bn3v,
                                               mw_in, mw_out, f1w, f1b, bn4g, bn4b, bn4m, bn4v,
                                               c1w, c1b, bn1g, bn1b, bn1m, bn1v,
                                               wA2h, wA3h, wInH, wOutH, f1H, wA1h, scbi);
  k123_conv123<<<dim3(512), dim3(1024), 0, stream>>>(x, wA1h, wA2h, wA3h, scbi, part);
  k4a_gemm_in<<<dim3(19, 4), dim3(256), 0, stream>>>(wInH, part, Z);
  k4b_pointwise<<<dim3(256), dim3(256), 0, stream>>>(Z, mconv_w, mconv_b, mdt_bias, mD, mnorm_w, yH);
  k4c_gemm_out<<<dim3(4, 4), dim3(256), 0, stream>>>(wOutH, yH, obH);
  k4d_head<<<dim3(4), dim3(256), 0, stream>>>(f1H, obH, scbi, f2w, f2b, outp);
}

// Round 8
// 87.146 us; speedup vs baseline: 1.9586x; 1.1595x over previous
//
#include <hip/hip_runtime.h>
#include <math.h>

#define EPS 1e-5f

typedef _Float16 f16x8 __attribute__((ext_vector_type(8)));
typedef _Float16 f16x4 __attribute__((ext_vector_type(4)));
typedef float    f32x4 __attribute__((ext_vector_type(4)));

// ---------------- K0: weight packing + BN coefficient prep ----------------
__global__ void k0_prep(const float* __restrict__ c2w, const float* __restrict__ c3w,
                        const float* __restrict__ c2b, const float* __restrict__ bn2g,
                        const float* __restrict__ bn2b, const float* __restrict__ bn2m,
                        const float* __restrict__ bn2v,
                        const float* __restrict__ c3b, const float* __restrict__ bn3g,
                        const float* __restrict__ bn3b, const float* __restrict__ bn3m,
                        const float* __restrict__ bn3v,
                        const float* __restrict__ mw_in, const float* __restrict__ mw_out,
                        const float* __restrict__ f1w, const float* __restrict__ f1b,
                        const float* __restrict__ bn4g, const float* __restrict__ bn4b,
                        const float* __restrict__ bn4m, const float* __restrict__ bn4v,
                        const float* __restrict__ c1w, const float* __restrict__ c1b,
                        const float* __restrict__ bn1g, const float* __restrict__ bn1b,
                        const float* __restrict__ bn1m, const float* __restrict__ bn1v,
                        _Float16* __restrict__ wA2h, _Float16* __restrict__ wA3h,
                        _Float16* __restrict__ wInH, _Float16* __restrict__ wOutH,
                        _Float16* __restrict__ f1H, _Float16* __restrict__ wA1h,
                        float* __restrict__ scbi) {
  int idx = blockIdx.x * blockDim.x + threadIdx.x;
  int stride = gridDim.x * blockDim.x;
  for (int i = idx; i < 172032; i += stride) {
    int j = i & 7; int t = i >> 3; int co = t & 127; int sg = t >> 7;
    int kglob = sg * 8 + j;
    int ci = kglob & 63, kk = kglob >> 6;
    wA2h[i] = (_Float16)c2w[(co * 64 + ci) * 21 + kk];
  }
  for (int i = idx; i < 294912; i += stride) {
    int j = i & 7; int t = i >> 3; int co = t & 255; int sg = t >> 8;
    int kglob = sg * 8 + j;
    int ci = kglob & 127, kk = kglob >> 7;
    wA3h[i] = (_Float16)c3w[(co * 128 + ci) * 9 + kk];
  }
  for (int i = idx; i < 1216 * 256; i += stride) {
    int row = i >> 8;
    wInH[i] = (row < 1160) ? (_Float16)mw_in[i] : (_Float16)0.f;
  }
  for (int i = idx; i < 256 * 512; i += stride) wOutH[i] = (_Float16)mw_out[i];
  for (int i = idx; i < 64 * 256; i += stride)  f1H[i]  = (_Float16)f1w[i];
  for (int i = idx; i < 4096; i += stride) {
    int kglob = i & 63, co = i >> 6;
    int r = kglob >> 4, q = kglob & 15;
    int k = 4 * q + r;
    wA1h[i] = (k < 51) ? (_Float16)c1w[co * 51 + k] : (_Float16)0.f;
  }
  if (idx < 128) {
    float sc = bn2g[idx] / sqrtf(bn2v[idx] + EPS);
    scbi[idx] = sc;
    scbi[128 + idx] = (c2b[idx] - bn2m[idx]) * sc + bn2b[idx];
  }
  if (idx < 256) {
    float sc = bn3g[idx] / sqrtf(bn3v[idx] + EPS);
    scbi[256 + idx] = sc;
    scbi[512 + idx] = (c3b[idx] - bn3m[idx]) * sc + bn3b[idx];
  }
  if (idx < 64) {
    float sc = bn4g[idx] / sqrtf(bn4v[idx] + EPS);
    scbi[768 + idx] = sc;
    scbi[832 + idx] = (f1b[idx] - bn4m[idx]) * sc + bn4b[idx];
  }
  if (idx >= 64 && idx < 128) {
    int c = idx - 64;
    float sc = bn1g[c] / sqrtf(bn1v[c] + EPS);
    scbi[896 + c] = sc;
    scbi[960 + c] = (c1b[c] - bn1m[c]) * sc + bn1b[c];
  }
}

// ---------------- K123: fused conv1+pool -> conv2 -> conv3 -> w-mean ----------------
// R8: exact R5 revert (87.4us verified: 8 waves, VGPR 64, no spill) plus
// s_setprio(1/0) around each 8-MFMA cluster. R6/R7 proved >4 waves/SIMD
// is closed (conv chain needs >64 VGPR -> spills). setprio rationale:
// conv2/conv3 K-loops have NO per-iteration barriers, so the 16
// resident waves/CU drift to different phases -- the independent-wave
// regime where T5 measured +4-7% (not the barrier-locked null regime).
// Zero register cost; cleanly separable from the revert baseline.
__global__ __launch_bounds__(512, 4) void k123_conv123(
    const float* __restrict__ x, const _Float16* __restrict__ wA1h,
    const _Float16* __restrict__ wA2h, const _Float16* __restrict__ wA3h,
    const float* __restrict__ scbi, float* __restrict__ part) {
  __shared__ float phx[4 * 980];                 // conv1 phase arrays x_r[t]
  __shared__ __align__(16) _Float16 buf[18432];  // xT [288][64] -> h2T [144][128]
  _Float16* xT  = buf;
  _Float16* h2T = buf;
  int br = blockIdx.x, tid = threadIdx.x;
  // ---- stage: zero phx and xT pad rows ----
  for (int i = tid; i < 3920; i += 512) phx[i] = 0.f;
  {
    float4 z4 = make_float4(0.f, 0.f, 0.f, 0.f);
    for (int i = tid; i < 80; i += 512)  ((float4*)xT)[i] = z4;            // rows 0..9
    for (int i = tid; i < 304; i += 512) ((float4*)(xT + 16000))[i] = z4;  // rows 250..287
  }
  __syncthreads();
  const float* xrow = x + (size_t)br * 3840;
  for (int i = tid; i < 960; i += 512) {
    float4 v = ((const float4*)xrow)[i];
    int g = 4 * i;
    #pragma unroll
    for (int c = 0; c < 4; ++c) {
      int gp = g + c + 25;                 // = 4t + r
      phx[(gp & 3) * 980 + (gp >> 2)] = ((const float*)&v)[c];
    }
  }
  int l = tid & 63, wv = tid >> 6;      // wv 0..7
  int lr = l & 15, lg = l >> 4;
  // ---- conv1 phase: 8 waves, per-wave w0 groups g = wv + 8*it (g<60) ----
  {
    f16x8 af1[2][4];
    #pragma unroll
    for (int s = 0; s < 2; ++s)
      #pragma unroll
      for (int mm = 0; mm < 4; ++mm)
        af1[s][mm] = *(const f16x8*)&wA1h[(mm * 16 + lr) * 64 + s * 32 + lg * 8];
    float scr[4][4], bir[4][4];
    #pragma unroll
    for (int mm = 0; mm < 4; ++mm)
      #pragma unroll
      for (int r2 = 0; r2 < 4; ++r2) {
        int co = mm * 16 + lg * 4 + r2;
        scr[mm][r2] = scbi[896 + co];
        bir[mm][r2] = scbi[960 + co];
      }
    __syncthreads();   // phx + pad zeros visible
    for (int it = 0; it < 8; ++it) {
      int g = wv + 8 * it;
      if (g < 60) {
        int w0 = g * 16;
        f32x4 acc1[4] = {};
        #pragma unroll
        for (int s = 0; s < 2; ++s) {
          int r = s * 2 + (lg >> 1), q0 = (lg & 1) * 8;
          const float* src = &phx[r * 980 + w0 + lr + q0];
          f16x8 bf;
          #pragma unroll
          for (int j = 0; j < 8; ++j) bf[j] = (_Float16)src[j];
          #pragma unroll
          for (int mm = 0; mm < 4; ++mm)
            acc1[mm] = __builtin_amdgcn_mfma_f32_16x16x32_f16(af1[s][mm], bf, acc1[mm], 0, 0, 0);
        }
        int pp = w0 / 4 + (lr >> 2);       // pooled index 0..239
        int p = pp + 10;                   // xT row
        int cpx = (p >> 1) & 7;
        #pragma unroll
        for (int mm = 0; mm < 4; ++mm) {
          int co0 = mm * 16 + lg * 4;
          f16x4 hv;
          #pragma unroll
          for (int r2 = 0; r2 < 4; ++r2) {
            float v0 = acc1[mm][r2] * scr[mm][r2] + bir[mm][r2];
            float m1 = fmaxf(v0, __shfl_xor(v0, 1));
            float m2 = fmaxf(m1, __shfl_xor(m1, 2));
            hv[r2] = (_Float16)fmaxf(m2, 0.f);
          }
          if ((lr & 3) == 0)
            *(f16x4*)&xT[p * 64 + ((co0 >> 3) ^ cpx) * 8 + (co0 & 7)] = hv;
        }
      }
    }
  }
  // ---- conv2 phase: wave = (co group wv>>1 of 32) x (w half wv&1 of 64) ----
  int cobase = (wv >> 1) * 32, wbase = (wv & 1) * 64;
  int arow2 = lg * 128 + cobase + lr;
  int wn[4], wn128[4];
  #pragma unroll
  for (int nn = 0; nn < 4; ++nn) { wn[nn] = wbase + nn * 16 + lr; wn128[nn] = wn[nn] * 128; }
  f32x4 acc[2][4] = {};
  const _Float16* wa2 = wA2h + (size_t)arow2 * 8;   // step s at wa2[s*4096 + mm*128]
  f16x8 afE0[2], afO0[2], afE1[2], afO1[2];         // parity sets: pair sp uses set sp&1
  afE0[0] = *(const f16x8*)&wa2[0];
  afE0[1] = *(const f16x8*)&wa2[128];
  afO0[0] = *(const f16x8*)&wa2[4096];
  afO0[1] = *(const f16x8*)&wa2[4096 + 128];
  afE1[0] = *(const f16x8*)&wa2[2 * 4096];
  afE1[1] = *(const f16x8*)&wa2[2 * 4096 + 128];
  afO1[0] = *(const f16x8*)&wa2[3 * 4096];
  afO1[1] = *(const f16x8*)&wa2[3 * 4096 + 128];
  __syncthreads();   // xT fully written
  #pragma unroll 1
  for (int spp = 0; spp < 10; ++spp) {
    // ---- even pair sp0 = 2*spp (set 0); prefetch pair sp0+2 into set 0 ----
    {
      int sp = 2 * spp;
      int sp64 = sp * 64, sph = sp >> 1;
      f16x8 bf0[4], bf1[4];
      #pragma unroll
      for (int nn = 0; nn < 4; ++nn) {
        int t = (wn[nn] + sph) & 7;
        int i0 = wn128[nn] + sp64 + ((lg ^ t) << 3);
        bf0[nn] = *(const f16x8*)&xT[i0];
        bf1[nn] = *(const f16x8*)&xT[i0 ^ 32];
      }
      __builtin_amdgcn_s_setprio(1);
      #pragma unroll
      for (int mm = 0; mm < 2; ++mm)
        #pragma unroll
        for (int nn = 0; nn < 4; ++nn)
          acc[mm][nn] = __builtin_amdgcn_mfma_f32_16x16x32_f16(afE0[mm], bf0[nn], acc[mm][nn], 0, 0, 0);
      __builtin_amdgcn_s_setprio(0);
      {
        const _Float16* w = wa2 + (size_t)(2 * sp + 4) * 4096;   // pair sp+2, even step
        afE0[0] = *(const f16x8*)&w[0];
        afE0[1] = *(const f16x8*)&w[128];
      }
      __builtin_amdgcn_s_setprio(1);
      #pragma unroll
      for (int mm = 0; mm < 2; ++mm)
        #pragma unroll
        for (int nn = 0; nn < 4; ++nn)
          acc[mm][nn] = __builtin_amdgcn_mfma_f32_16x16x32_f16(afO0[mm], bf1[nn], acc[mm][nn], 0, 0, 0);
      __builtin_amdgcn_s_setprio(0);
      {
        const _Float16* w = wa2 + (size_t)(2 * sp + 5) * 4096;   // pair sp+2, odd step
        afO0[0] = *(const f16x8*)&w[0];
        afO0[1] = *(const f16x8*)&w[128];
      }
    }
    // ---- odd pair sp1 = 2*spp+1 (set 1); prefetch pair sp1+2 (guard spp<9) ----
    {
      int sp = 2 * spp + 1;
      int sp64 = sp * 64, sph = sp >> 1;
      f16x8 bf0[4], bf1[4];
      #pragma unroll
      for (int nn = 0; nn < 4; ++nn) {
        int t = (wn[nn] + sph) & 7;
        int i0 = wn128[nn] + sp64 + ((lg ^ t) << 3);
        bf0[nn] = *(const f16x8*)&xT[i0];
        bf1[nn] = *(const f16x8*)&xT[i0 ^ 32];
      }
      __builtin_amdgcn_s_setprio(1);
      #pragma unroll
      for (int mm = 0; mm < 2; ++mm)
        #pragma unroll
        for (int nn = 0; nn < 4; ++nn)
          acc[mm][nn] = __builtin_amdgcn_mfma_f32_16x16x32_f16(afE1[mm], bf0[nn], acc[mm][nn], 0, 0, 0);
      __builtin_amdgcn_s_setprio(0);
      if (spp < 9) {
        const _Float16* w = wa2 + (size_t)(2 * sp + 4) * 4096;
        afE1[0] = *(const f16x8*)&w[0];
        afE1[1] = *(const f16x8*)&w[128];
      }
      __builtin_amdgcn_s_setprio(1);
      #pragma unroll
      for (int mm = 0; mm < 2; ++mm)
        #pragma unroll
        for (int nn = 0; nn < 4; ++nn)
          acc[mm][nn] = __builtin_amdgcn_mfma_f32_16x16x32_f16(afO1[mm], bf1[nn], acc[mm][nn], 0, 0, 0);
      __builtin_amdgcn_s_setprio(0);
      if (spp < 9) {
        const _Float16* w = wa2 + (size_t)(2 * sp + 5) * 4096;
        afO1[0] = *(const f16x8*)&w[0];
        afO1[1] = *(const f16x8*)&w[128];
      }
    }
  }
  // ---- tail pair 20 (set 0, prefetched during spp=9 even half) ----
  {
    int sp = 20;
    int sp64 = sp * 64, sph = sp >> 1;
    f16x8 bf0[4], bf1[4];
    #pragma unroll
    for (int nn = 0; nn < 4; ++nn) {
      int t = (wn[nn] + sph) & 7;
      int i0 = wn128[nn] + sp64 + ((lg ^ t) << 3);
      bf0[nn] = *(const f16x8*)&xT[i0];
      bf1[nn] = *(const f16x8*)&xT[i0 ^ 32];
    }
    __builtin_amdgcn_s_setprio(1);
    #pragma unroll
    for (int mm = 0; mm < 2; ++mm)
      #pragma unroll
      for (int nn = 0; nn < 4; ++nn)
        acc[mm][nn] = __builtin_amdgcn_mfma_f32_16x16x32_f16(afE0[mm], bf0[nn], acc[mm][nn], 0, 0, 0);
    #pragma unroll
    for (int mm = 0; mm < 2; ++mm)
      #pragma unroll
      for (int nn = 0; nn < 4; ++nn)
        acc[mm][nn] = __builtin_amdgcn_mfma_f32_16x16x32_f16(afO0[mm], bf1[nn], acc[mm][nn], 0, 0, 0);
    __builtin_amdgcn_s_setprio(0);
  }
  __syncthreads();   // all xT reads done; buf may now be overwritten as h2T
  // conv2 epilogue: BN+ReLU -> h2T (aliased buf), plus pad-row zeroing
  {
    float4 z4 = make_float4(0.f, 0.f, 0.f, 0.f);
    for (int i = tid; i < 384; i += 512) {
      int h8 = (i < 64) ? i : (1984 + (i - 64));
      *(float4*)&h2T[h8 * 8] = z4;
    }
    const float* sc2 = scbi;
    const float* bi2 = scbi + 128;
    #pragma unroll
    for (int mm = 0; mm < 2; ++mm) {
      int co0 = cobase + mm * 16 + lg * 4;
      float s0 = sc2[co0], s1 = sc2[co0 + 1], s2 = sc2[co0 + 2], s3 = sc2[co0 + 3];
      float b0 = bi2[co0], b1 = bi2[co0 + 1], b2 = bi2[co0 + 2], b3 = bi2[co0 + 3];
      #pragma unroll
      for (int nn = 0; nn < 4; ++nn) {
        int w = wn[nn];
        if (w < 120) {
          int p3 = 4 + w;
          f16x4 hv;
          hv[0] = (_Float16)fmaxf(acc[mm][nn][0] * s0 + b0, 0.f);
          hv[1] = (_Float16)fmaxf(acc[mm][nn][1] * s1 + b1, 0.f);
          hv[2] = (_Float16)fmaxf(acc[mm][nn][2] * s2 + b2, 0.f);
          hv[3] = (_Float16)fmaxf(acc[mm][nn][3] * s3 + b3, 0.f);
          int cp = (co0 >> 3) ^ ((p3 >> 1) & 15);
          *(f16x4*)&h2T[p3 * 128 + cp * 8 + (co0 & 7)] = hv;
        }
      }
    }
  }
  // ---- conv3 phase: wave wv owns co chunk wv*32 (32 co), all 64 w (mask w<60) ----
  int cobase3 = wv * 32;
  int arow3 = lg * 256 + cobase3 + lr;
  const _Float16* wa3 = wA3h + (size_t)arow3 * 8;   // step s at wa3[s*8192 + mm*128]
  int wn3[4], wn256[4];
  #pragma unroll
  for (int nn = 0; nn < 4; ++nn) { wn3[nn] = nn * 16 + lr; wn256[nn] = wn3[nn] * 256; }
  f32x4 acc3[2][4] = {};
  f16x8 ag[4][2];
  #pragma unroll
  for (int j = 0; j < 4; ++j) {
    ag[j][0] = *(const f16x8*)&wa3[(size_t)j * 8192];
    ag[j][1] = *(const f16x8*)&wa3[(size_t)j * 8192 + 128];
  }
  __syncthreads();   // h2T writes visible
  #pragma unroll 1
  for (int q = 0; q < 9; ++q) {             // quad of K-steps s=4q..4q+3 (kk=q)
    int q128 = q << 7;
    int qh = q >> 1;
    int i0[4];
    #pragma unroll
    for (int nn = 0; nn < 4; ++nn) {
      int t = (wn3[nn] + qh) & 15;
      i0[nn] = wn256[nn] + q128 + ((lg ^ t) << 3);  // j=0 (cc=lg)
    }
    #pragma unroll
    for (int j = 0; j < 4; ++j) {
      f16x8 bg[4];
      #pragma unroll
      for (int nn = 0; nn < 4; ++nn)
        bg[nn] = *(const f16x8*)&h2T[i0[nn] ^ (j << 5)];  // cc=j*4+lg -> ^(j*32) halves
      __builtin_amdgcn_s_setprio(1);
      #pragma unroll
      for (int mm = 0; mm < 2; ++mm)
        #pragma unroll
        for (int nn = 0; nn < 4; ++nn)
          acc3[mm][nn] = __builtin_amdgcn_mfma_f32_16x16x32_f16(ag[j][mm], bg[nn], acc3[mm][nn], 0, 0, 0);
      __builtin_amdgcn_s_setprio(0);
      if (q < 8) {
        const _Float16* wsrc = wa3 + (size_t)(4 * (q + 1) + j) * 8192;
        ag[j][0] = *(const f16x8*)&wsrc[0];
        ag[j][1] = *(const f16x8*)&wsrc[128];
      }
    }
  }
  // conv3 epilogue: BN+ReLU, masked w-sum, 16-lane reduce, direct global write
  {
    const float* sc3 = scbi + 256;
    const float* bi3 = scbi + 512;
    #pragma unroll
    for (int mm = 0; mm < 2; ++mm) {
      #pragma unroll
      for (int r = 0; r < 4; ++r) {
        int co = cobase3 + mm * 16 + lg * 4 + r;
        float sc = sc3[co], bi = bi3[co];
        float sum = 0.f;
        #pragma unroll
        for (int nn = 0; nn < 4; ++nn) {
          int w = wn3[nn];
          float val = fmaxf(acc3[mm][nn][r] * sc + bi, 0.f);
          if (w < 60) sum += val;
        }
        sum += __shfl_xor(sum, 1);
        sum += __shfl_xor(sum, 2);
        sum += __shfl_xor(sum, 4);
        sum += __shfl_xor(sum, 8);
        if (lr == 0) part[(size_t)br * 256 + co] = sum;
      }
    }
  }
}

// ---------------- K4a: Z = feat @ mw_in^T (feat computed in-block from part) ----------------
__global__ __launch_bounds__(256) void k4a_gemm_in(
    const _Float16* __restrict__ wInH, const float* __restrict__ part,
    float* __restrict__ Z) {
  __shared__ __align__(16) _Float16 featL[64][264];  // padded rows
  int tid = threadIdx.x;
  int mbase = blockIdx.x * 64, nbase = blockIdx.y * 64;
  for (int i = tid; i < 64 * 256; i += 256) {
    int b = i >> 8, c = i & 255;
    float s0 = part[((size_t)(nbase + b) * 2 + 0) * 256 + c];
    float s1 = part[((size_t)(nbase + b) * 2 + 1) * 256 + c];
    featL[b][c] = (_Float16)((s0 + s1) * (1.f / 120.f));
  }
  int l = tid & 63, wv = tid >> 6;
  int lr = l & 15, lg = l >> 4;
  int mo = (wv & 1) * 32, no = (wv >> 1) * 32;
  f32x4 acc[2][2] = {};
  __syncthreads();
  for (int s = 0; s < 8; ++s) {
    f16x8 af[2], bf[2];
    #pragma unroll
    for (int mm = 0; mm < 2; ++mm) {
      int row = mbase + mo + mm * 16 + lr;
      af[mm] = *(const f16x8*)&wInH[(size_t)row * 256 + s * 32 + lg * 8];
    }
    #pragma unroll
    for (int nn = 0; nn < 2; ++nn) {
      int b = no + nn * 16 + lr;
      bf[nn] = *(const f16x8*)&featL[b][s * 32 + lg * 8];
    }
    #pragma unroll
    for (int mm = 0; mm < 2; ++mm)
      #pragma unroll
      for (int nn = 0; nn < 2; ++nn)
        acc[mm][nn] = __builtin_amdgcn_mfma_f32_16x16x32_f16(af[mm], bf[nn], acc[mm][nn], 0, 0, 0);
  }
  #pragma unroll
  for (int mm = 0; mm < 2; ++mm) {
    int row0 = mbase + mo + mm * 16 + lg * 4;
    #pragma unroll
    for (int nn = 0; nn < 2; ++nn) {
      int b = nbase + no + nn * 16 + lr;
      *(float4*)&Z[(size_t)b * 1216 + row0] = *(float4*)&acc[mm][nn];
    }
  }
}

// ---------------- K4b: per-batch pointwise mamba core ----------------
__global__ __launch_bounds__(256) void k4b_pointwise(
    const float* __restrict__ Z,
    const float* __restrict__ mconv_w, const float* __restrict__ mconv_b,
    const float* __restrict__ mdt_bias, const float* __restrict__ mD,
    const float* __restrict__ mnorm_w, _Float16* __restrict__ yH) {
  __shared__ float zx[1160];
  __shared__ float red4[4];
  __shared__ float sBs;
  __shared__ float coef[8];
  int tid = threadIdx.x;
  int b = blockIdx.x;
  const float* zsrc = Z + (size_t)b * 1216;
  for (int row = tid; row < 1160; row += 256) zx[row] = zsrc[row];
  __syncthreads();
  for (int c = tid; c < 640; c += 256) {
    float t = zx[512 + c] * mconv_w[c * 4 + 3] + mconv_b[c];
    zx[512 + c] = t / (1.f + expf(-t));
  }
  __syncthreads();
  if (tid < 64) {
    float p = zx[1024 + tid] * zx[1088 + tid];
    #pragma unroll
    for (int off = 32; off > 0; off >>= 1) p += __shfl_xor(p, off, 64);
    if (tid == 0) sBs = p;
  }
  __syncthreads();
  if (tid < 8) {
    float u = zx[1152 + tid] + mdt_bias[tid];
    float sp = (u > 20.f) ? u : log1pf(expf(u));
    coef[tid] = sp * sBs + mD[tid];
  }
  __syncthreads();
  float ssq = 0.f;
  #pragma unroll
  for (int ii = 0; ii < 2; ++ii) {
    int i = tid + ii * 256;
    float z = zx[i];
    float t = zx[512 + i] * coef[i >> 6] * (z / (1.f + expf(-z)));
    zx[i] = t;
    ssq += t * t;
  }
  #pragma unroll
  for (int off = 32; off > 0; off >>= 1) ssq += __shfl_xor(ssq, off, 64);
  if ((tid & 63) == 0) red4[tid >> 6] = ssq;
  __syncthreads();
  {
    float total = red4[0] + red4[1] + red4[2] + red4[3];
    float rn = 1.f / sqrtf(total * (1.f / 512.f) + EPS);
    #pragma unroll
    for (int ii = 0; ii < 2; ++ii) {
      int i = tid + ii * 256;
      float y = zx[i] * rn * mnorm_w[i];
      yH[(size_t)b * 512 + i] = (_Float16)y;
    }
  }
}

// ---------------- K4c: ob = y @ mw_out^T as MFMA GEMM ----------------
__global__ __launch_bounds__(256) void k4c_gemm_out(
    const _Float16* __restrict__ wOutH, const _Float16* __restrict__ yH,
    _Float16* __restrict__ obH) {
  int tid = threadIdx.x;
  int mbase = blockIdx.x * 64, nbase = blockIdx.y * 64;
  int l = tid & 63, wv = tid >> 6;
  int lr = l & 15, lg = l >> 4;
  int mo = (wv & 1) * 32, no = (wv >> 1) * 32;
  f32x4 acc[2][2] = {};
  for (int s = 0; s < 16; ++s) {
    f16x8 af[2], bf[2];
    #pragma unroll
    for (int mm = 0; mm < 2; ++mm) {
      int row = mbase + mo + mm * 16 + lr;
      af[mm] = *(const f16x8*)&wOutH[(size_t)row * 512 + s * 32 + lg * 8];
    }
    #pragma unroll
    for (int nn = 0; nn < 2; ++nn) {
      int b = nbase + no + nn * 16 + lr;
      bf[nn] = *(const f16x8*)&yH[(size_t)b * 512 + s * 32 + lg * 8];
    }
    #pragma unroll
    for (int mm = 0; mm < 2; ++mm)
      #pragma unroll
      for (int nn = 0; nn < 2; ++nn)
        acc[mm][nn] = __builtin_amdgcn_mfma_f32_16x16x32_f16(af[mm], bf[nn], acc[mm][nn], 0, 0, 0);
  }
  #pragma unroll
  for (int mm = 0; mm < 2; ++mm) {
    int row0 = mbase + mo + mm * 16 + lg * 4;
    #pragma unroll
    for (int nn = 0; nn < 2; ++nn) {
      int b = nbase + no + nn * 16 + lr;
      f16x4 hv;
      hv[0] = (_Float16)acc[mm][nn][0];
      hv[1] = (_Float16)acc[mm][nn][1];
      hv[2] = (_Float16)acc[mm][nn][2];
      hv[3] = (_Float16)acc[mm][nn][3];
      *(f16x4*)&obH[(size_t)b * 256 + row0] = hv;
    }
  }
}

// ---------------- K4d: head ----------------
__global__ __launch_bounds__(256) void k4d_head(
    const _Float16* __restrict__ f1H, const _Float16* __restrict__ obH,
    const float* __restrict__ scbi, const float* __restrict__ f2w,
    const float* __restrict__ f2b, float* __restrict__ outp) {
  int tid = threadIdx.x;
  int nbase = blockIdx.x * 64;
  int l = tid & 63, wv = tid >> 6;
  int lr = l & 15, lg = l >> 4;
  int bcol = nbase + wv * 16 + lr;
  f32x4 acc[4] = {};
  for (int s = 0; s < 8; ++s) {
    f16x8 bf = *(const f16x8*)&obH[(size_t)bcol * 256 + s * 32 + lg * 8];
    #pragma unroll
    for (int mm = 0; mm < 4; ++mm) {
      f16x8 af = *(const f16x8*)&f1H[(size_t)(mm * 16 + lr) * 256 + s * 32 + lg * 8];
      acc[mm] = __builtin_amdgcn_mfma_f32_16x16x32_f16(af, bf, acc[mm], 0, 0, 0);
    }
  }
  float psum = 0.f;
  #pragma unroll
  for (int mm = 0; mm < 4; ++mm) {
    #pragma unroll
    for (int r = 0; r < 4; ++r) {
      int row = mm * 16 + lg * 4 + r;
      float val = acc[mm][r] * scbi[768 + row] + scbi[832 + row];
      val = fmaxf(val, 0.f);
      psum += val * f2w[row];
    }
  }
  psum += __shfl_xor(psum, 16, 64);
  psum += __shfl_xor(psum, 32, 64);
  if (l < 16) outp[bcol] = psum + f2b[0];
}

extern "C" void kernel_launch(void* const* d_in, const int* in_sizes, int n_in,
                              void* d_out, int out_size, void* d_ws, size_t ws_size,
                              hipStream_t stream) {
  const float* x    = (const float*)d_in[0];
  const float* c1w  = (const float*)d_in[1];
  const float* c1b  = (const float*)d_in[2];
  const float* bn1g = (const float*)d_in[3];
  const float* bn1b = (const float*)d_in[4];
  const float* bn1m = (const float*)d_in[5];
  const float* bn1v = (const float*)d_in[6];
  const float* c2w  = (const float*)d_in[7];
  const float* c2b  = (const float*)d_in[8];
  const float* bn2g = (const float*)d_in[9];
  const float* bn2b = (const float*)d_in[10];
  const float* bn2m = (const float*)d_in[11];
  const float* bn2v = (const float*)d_in[12];
  const float* c3w  = (const float*)d_in[13];
  const float* c3b  = (const float*)d_in[14];
  const float* bn3g = (const float*)d_in[15];
  const float* bn3b = (const float*)d_in[16];
  const float* bn3m = (const float*)d_in[17];
  const float* bn3v = (const float*)d_in[18];
  const float* mw_in    = (const float*)d_in[19];
  const float* mconv_w  = (const float*)d_in[20];
  const float* mconv_b  = (const float*)d_in[21];
  const float* mdt_bias = (const float*)d_in[22];
  // d_in[23] = mA_log: unused (L=1 scan from h0=0 makes dA dead)
  const float* mD       = (const float*)d_in[24];
  const float* mnorm_w  = (const float*)d_in[25];
  const float* mw_out   = (const float*)d_in[26];
  const float* f1w  = (const float*)d_in[27];
  const float* f1b  = (const float*)d_in[28];
  const float* bn4g = (const float*)d_in[29];
  const float* bn4b = (const float*)d_in[30];
  const float* bn4m = (const float*)d_in[31];
  const float* bn4v = (const float*)d_in[32];
  const float* f2w  = (const float*)d_in[33];
  const float* f2b  = (const float*)d_in[34];

  _Float16* p1h   = (_Float16*)d_ws;             // unused after k123 fusion (layout stability)
  _Float16* h2h   = p1h + (size_t)512 * 18432;   // unused
  _Float16* wA2h  = h2h + (size_t)512 * 18432;
  _Float16* wA3h  = wA2h + 172032;
  _Float16* wInH  = wA3h + 294912;
  _Float16* wOutH = wInH + (size_t)1216 * 256;
  _Float16* f1H   = wOutH + (size_t)256 * 512;
  _Float16* featH = f1H + 64 * 256;              // unused
  _Float16* yH    = featH + 256 * 256;
  _Float16* obH   = yH + (size_t)256 * 512;
  _Float16* wA1h  = obH + 256 * 256;
  float*    scbi  = (float*)(wA1h + 4096);
  float*    part  = scbi + 1024;
  float*    Z     = part + (size_t)512 * 256;
  float*    outp  = (float*)d_out;

  k0_prep<<<dim3(512), dim3(256), 0, stream>>>(c2w, c3w, c2b, bn2g, bn2b, bn2m, bn2v,
                                               c3b, bn3g, bn3b, bn3m, bn3v,
                                               mw_in, mw_out, f1w, f1b, bn4g, bn4b, bn4m, bn4v,
                                               c1w, c1b, bn1g, bn1b, bn1m, bn1v,
                                               wA2h, wA3h, wInH, wOutH, f1H, wA1h, scbi);
  k123_conv123<<<dim3(512), dim3(512), 0, stream>>>(x, wA1h, wA2h, wA3h, scbi, part);
  k4a_gemm_in<<<dim3(19, 4), dim3(256), 0, stream>>>(wInH, part, Z);
  k4b_pointwise<<<dim3(256), dim3(256), 0, stream>>>(Z, mconv_w, mconv_b, mdt_bias, mD, mnorm_w, yH);
  k4c_gemm_out<<<dim3(4, 4), dim3(256), 0, stream>>>(wOutH, yH, obH);
  k4d_head<<<dim3(4), dim3(256), 0, stream>>>(f1H, obH, scbi, f2w, f2b, outp);
}